// Round 5
// baseline (531.461 us; speedup 1.0000x reference)
//
#include <hip/hip_runtime.h>

#define BIG_Z_F 1000000.0f
#define N_MESH 8

// Native Clang vector types — required by __builtin_nontemporal_* (HIP's
// float4/int4 are structs and are rejected by the builtin).
typedef float f4 __attribute__((ext_vector_type(4)));
typedef int   i4 __attribute__((ext_vector_type(4)));
typedef unsigned char uc4 __attribute__((ext_vector_type(4)));

// R14: DIAGNOSTIC ROUND (intentionally ~2x slower headline).
// R13 exonerated NT stores (plain was +24us). Four theories dead; two
// survive and are indistinguishable without per-kernel counters:
//   (a) kernel B runs at ~2.2 TB/s effective (some amplification) — ~100us
//       recoverable;  (b) ~100us of dur_us is harness fixed cost and B is
//       already near the ~59us byte floor — nothing recoverable.
// The top-5 report only shows dispatches slower than the ~205us poison
// fills, so B (< 203us) has been invisible all session. This round runs B's
// work 3x IDEMPOTENTLY (grid.y=24, n=blockIdx.y&7; replicas write identical
// bytes; faceflag writes only 1s — benign races) so that 3x B_real > 207us
// iff B_real > 69us, forcing B into the top-5 WITH its true FETCH_SIZE /
// WRITE_SIZE / VALUBusy / Occupancy / VGPR_Count.
//   - B appears  -> B_real = dur/3; WRITE_SIZE/3 vs 310MB and FETCH_SIZE/3
//                   vs ~50MB test write/fetch amplification directly.
//   - B absent   -> B_real < 69us -> the 387us wall is harness fixed cost;
//                   revert to R9 and stop.
// Everything except the replication is byte-exact R9 (NT everywhere).

// ---------------------------------------------------------------------------
// Kernel A: per-4-pixel cross-mesh reduction + ws zero-init. (R9 exact)
// ---------------------------------------------------------------------------
__global__ __launch_bounds__(256) void raster_reduce(
    const f4* __restrict__ zbuf4,   // (N, HW/4)
    f4* __restrict__ maskO4,        // (N, HW/4)
    f4* __restrict__ zbO4,          // (N, HW/4)
    uc4* __restrict__ win4,         // (HW/4) ws
    int* __restrict__ faceflag,     // (F+1) ws — zeroed here, used by B
    float* __restrict__ vv,         // (V) out — zeroed here, used by vert_vis
    const int* __restrict__ mdp,    // scalar mask_duplicate
    int HW4, int F, int V)
{
    const int q = blockIdx.x * blockDim.x + threadIdx.x;
    if (q >= HW4) return;

    // Folded zero-init (A runs before B / vert_vis; stream-ordered).
    if (q <= F) faceflag[q] = 0;
    if (q < V)  vv[q] = 0.0f;

    const int md = *mdp;

    float z[N_MESH][4];
    #pragma unroll
    for (int n = 0; n < N_MESH; ++n) {
        const f4 v = __builtin_nontemporal_load(&zbuf4[n * HW4 + q]);
        z[n][0] = v.x; z[n][1] = v.y; z[n][2] = v.z; z[n][3] = v.w;
    }

    bool dup0[4]; int bidx[4];
    #pragma unroll
    for (int j = 0; j < 4; ++j) {
        int count = 0; float best = __builtin_inff(); int bi = 0;
        #pragma unroll
        for (int n = 0; n < N_MESH; ++n) {
            const float zv = z[n][j];
            count += (zv > -1.0f) ? 1 : 0;
            const float t = (zv < 0.0f) ? BIG_Z_F : zv;
            if (t < best) { best = t; bi = n; }   // strict < => first-win tie
        }
        dup0[j] = (count > 1);
        bidx[j] = bi;
    }

    #pragma unroll
    for (int n = 0; n < N_MESH; ++n) {
        f4 m, zb;
        #pragma unroll
        for (int j = 0; j < 4; ++j) {
            const bool dup = dup0[j] && ((md != 0) || (n != bidx[j]));
            m[j]  = (z[n][j] >= 0.0f) ? 1.0f : 0.0f;
            zb[j] = dup ? -1.0f : z[n][j];
        }
        __builtin_nontemporal_store(m,  &maskO4[n * HW4 + q]);
        __builtin_nontemporal_store(zb, &zbO4[n * HW4 + q]);
    }
    uc4 w;
    w.x = dup0[0] ? (unsigned char)bidx[0] : (unsigned char)0xFF;
    w.y = dup0[1] ? (unsigned char)bidx[1] : (unsigned char)0xFF;
    w.z = dup0[2] ? (unsigned char)bidx[2] : (unsigned char)0xFF;
    w.w = dup0[3] ? (unsigned char)bidx[3] : (unsigned char)0xFF;
    win4[q] = w;
}

// ---------------------------------------------------------------------------
// Kernel B: per-(mesh, 4 pixels). R9-exact work, replicated 3x via grid.y=24
// with n = blockIdx.y & 7 (idempotent; same values stored by each replica).
// ---------------------------------------------------------------------------
__global__ __launch_bounds__(256) void raster_interp(
    const i4* __restrict__ p2f4,    // (N, HW/4)
    const f4* __restrict__ bary4,   // (N, HW/4, 3)
    const f4* __restrict__ dists4,  // (N, HW/4)
    const float* __restrict__ fmem, // (F,3,C)
    const uc4* __restrict__ win4,   // (HW/4)
    const int* __restrict__ mdp,
    f4* __restrict__ out_map4,      // (N,C,HW/4)
    f4* __restrict__ pO4,           // (N, HW/4)
    f4* __restrict__ dO4,           // (N, HW/4)
    f4* __restrict__ bcO4,          // (N, HW/4, 3)
    int* __restrict__ faceflag,     // (F+1) ws, pre-zeroed; slot F = dummy
    int HW4, int C, int F)
{
    const int q = blockIdx.x * blockDim.x + threadIdx.x;
    if (q >= HW4) return;
    const int n    = blockIdx.y & 7;     // R14: 3 idempotent replicas
    const int idx4 = n * HW4 + q;
    const int md   = *mdp;

    const uc4 wv = win4[q];
    const unsigned char w[4] = { wv.x, wv.y, wv.z, wv.w };

    const i4 praw = __builtin_nontemporal_load(&p2f4[idx4]);
    const f4 drw  = __builtin_nontemporal_load(&dists4[idx4]);
    const f4 bv0  = __builtin_nontemporal_load(&bary4[idx4 * 3 + 0]); // p0.xyz p1.x
    const f4 bv1  = __builtin_nontemporal_load(&bary4[idx4 * 3 + 1]); // p1.yz  p2.xy
    const f4 bv2  = __builtin_nontemporal_load(&bary4[idx4 * 3 + 2]); // p2.z   p3.xyz
    const int   pr[4] = { praw.x, praw.y, praw.z, praw.w };
    const float dr[4] = { drw.x, drw.y, drw.z, drw.w };
    const float br[4][3] = {
        { bv0.x, bv0.y, bv0.z },
        { bv0.w, bv1.x, bv1.y },
        { bv1.z, bv1.w, bv2.x },
        { bv2.y, bv2.z, bv2.w },
    };

    float bst[4][3];   // values stored to bcO (dup -> -1)
    float bc[4][3];    // compute coefficients (invalid -> 0 => out = 0)
    int   safe[4];
    f4 pOv, dOv;
    #pragma unroll
    for (int j = 0; j < 4; ++j) {
        const bool dup   = (w[j] != 0xFF) && ((md != 0) || (n != (int)w[j]));
        const int  p     = dup ? -1 : pr[j];
        const bool valid = (p >= 0);
        #pragma unroll
        for (int k = 0; k < 3; ++k) {
            bst[j][k] = dup ? -1.0f : br[j][k];
            bc[j][k]  = valid ? bst[j][k] : 0.0f;
        }
        safe[j] = valid ? p : 0;
        pOv[j]  = (float)p;
        dOv[j]  = dup ? -1.0f : dr[j];
        faceflag[valid ? p : F] = 1;   // branchless scatter; slot F = dummy
    }
    __builtin_nontemporal_store(pOv, &pO4[idx4]);
    __builtin_nontemporal_store(dOv, &dO4[idx4]);
    {
        f4 c0, c1, c2;
        c0.x = bst[0][0]; c0.y = bst[0][1]; c0.z = bst[0][2]; c0.w = bst[1][0];
        c1.x = bst[1][1]; c1.y = bst[1][2]; c1.z = bst[2][0]; c1.w = bst[2][1];
        c2.x = bst[2][2]; c2.y = bst[3][0]; c2.z = bst[3][1]; c2.w = bst[3][2];
        __builtin_nontemporal_store(c0, &bcO4[idx4 * 3 + 0]);
        __builtin_nontemporal_store(c1, &bcO4[idx4 * 3 + 1]);
        __builtin_nontemporal_store(c2, &bcO4[idx4 * 3 + 2]);
    }

    const float* ab[4];
    #pragma unroll
    for (int j = 0; j < 4; ++j)
        ab[j] = fmem + (size_t)safe[j] * 3 * C;

    #pragma unroll
    for (int c4 = 0; c4 < 32; c4 += 4) {     // C == 32
        f4 r[4];   // r[j] = channels c4..c4+3 of pixel j (channel-major)
        #pragma unroll
        for (int j = 0; j < 4; ++j) {
            const float* a = ab[j];
            const f4 a0 = *(const f4*)(a + c4);
            const f4 a1 = *(const f4*)(a + C + c4);
            const f4 a2 = *(const f4*)(a + 2 * C + c4);
            r[j] = bc[j][0] * a0 + bc[j][1] * a1 + bc[j][2] * a2;
        }
        #pragma unroll
        for (int k = 0; k < 4; ++k) {        // transpose to pixel-major
            f4 o;
            o.x = r[0][k]; o.y = r[1][k]; o.z = r[2][k]; o.w = r[3][k];
            __builtin_nontemporal_store(o, &out_map4[(size_t)(n * C + c4 + k) * HW4 + q]);
        }
    }
}

// Scatter vertex visibility from face-visibility flags. (R9 exact)
__global__ __launch_bounds__(256) void vert_vis(
    const int* __restrict__ faceflag,
    const int* __restrict__ pfaces,     // (F,3)
    float* __restrict__ vv,             // (V), pre-zeroed by kernel A
    int F)
{
    const int f = blockIdx.x * blockDim.x + threadIdx.x;
    if (f >= F) return;
    if (faceflag[f]) {
        vv[pfaces[f * 3 + 0]] = 1.0f;
        vv[pfaces[f * 3 + 1]] = 1.0f;
        vv[pfaces[f * 3 + 2]] = 1.0f;
    }
}

extern "C" void kernel_launch(void* const* d_in, const int* in_sizes, int n_in,
                              void* d_out, int out_size, void* d_ws, size_t ws_size,
                              hipStream_t stream) {
    const float* zbuf   = (const float*)d_in[0];
    const int*   p2f    = (const int*)  d_in[1];
    const float* bary   = (const float*)d_in[2];
    const float* dists  = (const float*)d_in[3];
    const float* fmem   = (const float*)d_in[4];
    const int*   pfaces = (const int*)  d_in[5];
    // d_in[6] = num_verts (device scalar; V derived from out_size instead)
    const int*   mdp    = (const int*)  d_in[7];

    const long long P  = in_sizes[0];        // N*H*W*K = 2097152
    const int HW  = (int)(P / N_MESH);       // 262144 pixels
    const int HW4 = HW / 4;                  // 65536
    const int F3  = in_sizes[5];             // F*3
    const int F   = F3 / 3;                  // 20000
    const int C   = in_sizes[4] / F3;        // 32
    const int V   = (int)((long long)out_size - P * C - 7 * P);  // 10002

    float* out     = (float*)d_out;
    float* out_map = out;                    // P*C
    float* vv      = out_map + P * C;        // V
    float* maskO   = vv + V;                 // P
    float* zbO     = maskO + P;              // P
    float* pO      = zbO + P;                // P
    float* dO      = pO + P;                 // P
    float* bcO     = dO + P;                 // 3P

    int* faceflag = (int*)d_ws;                 // F+1 ints (slot F = dummy)
    uc4* win4     = (uc4*)(faceflag + F + 4);   // HW bytes

    raster_reduce<<<dim3(HW4 / 256), dim3(256), 0, stream>>>(
        (const f4*)zbuf, (f4*)maskO, (f4*)zbO, win4, faceflag, vv, mdp,
        HW4, F, V);

    // R14 diagnostic: grid.y = 24 -> 3 idempotent replicas of each n-plane.
    raster_interp<<<dim3(HW4 / 256, 3 * N_MESH), dim3(256), 0, stream>>>(
        (const i4*)p2f, (const f4*)bary, (const f4*)dists, fmem,
        (const uc4*)win4, mdp,
        (f4*)out_map, (f4*)pO, (f4*)dO, (f4*)bcO,
        faceflag, HW4, C, F);

    vert_vis<<<dim3((F + 255) / 256), dim3(256), 0, stream>>>(
        faceflag, pfaces, vv, F);
}

// Round 6
// 388.295 us; speedup vs baseline: 1.3687x; 1.3687x over previous
//
#include <hip/hip_runtime.h>

#define BIG_Z_F 1000000.0f
#define N_MESH 8

// Native Clang vector types — required by __builtin_nontemporal_* (HIP's
// float4/int4 are structs and are rejected by the builtin).
typedef float f4 __attribute__((ext_vector_type(4)));
typedef float f2 __attribute__((ext_vector_type(2)));
typedef int   i4 __attribute__((ext_vector_type(4)));
typedef unsigned char uc4 __attribute__((ext_vector_type(4)));
typedef unsigned char uc2 __attribute__((ext_vector_type(2)));

// R15: targeted polish on the R9 base, informed by R14's forced-visibility
// counters (3x-replicated B: 233us -> B_real ~77.7us @ 5.1 TB/s, write
// amplification NONE, VALU 7.4%). Fixed-cost model confirmed: dur ~= fill
// (205) + A(~15) + B(~77) + vv(~5) + ~80us harness residue. Controllable
// slack ~= 30us. Two measured/accounted levers, nothing else changed:
//  1. Kernel A was wave-starved: 256 blocks = 1 wave/SIMD. Now 2 px/thread
//     (512 blocks, 2048 waves) — same bytes, double latency hiding.
//  2. Kernel B's branchless faceflag scatter issued 16.8M stores, ~14.7M of
//     them to the single dummy slot F. Now predicated: ~2.1M stores total.
// Ledger: R9 386.9 best; fusion (R10 +8), 1px/thread (R11 +18), plain
// stores (R12/R13 +24..+44) all regressed — do not revisit.

// ---------------------------------------------------------------------------
// Kernel A: per-2-pixel cross-mesh reduction + ws zero-init.
// win[j] = dup0 ? argmin : 0xFF.
// ---------------------------------------------------------------------------
__global__ __launch_bounds__(256) void raster_reduce(
    const f2* __restrict__ zbuf2,   // (N, HW/2)
    f2* __restrict__ maskO2,        // (N, HW/2)
    f2* __restrict__ zbO2,          // (N, HW/2)
    uc2* __restrict__ win2,         // (HW/2) ws
    int* __restrict__ faceflag,     // (F+1) ws — zeroed here, used by B
    float* __restrict__ vv,         // (V) out — zeroed here, used by vert_vis
    const int* __restrict__ mdp,    // scalar mask_duplicate
    int HW2, int F, int V)
{
    const int q = blockIdx.x * blockDim.x + threadIdx.x;
    if (q >= HW2) return;

    // Folded zero-init (A runs before B / vert_vis; stream-ordered).
    if (q <= F) faceflag[q] = 0;
    if (q < V)  vv[q] = 0.0f;

    const int md = *mdp;

    float z[N_MESH][2];
    #pragma unroll
    for (int n = 0; n < N_MESH; ++n) {
        const f2 v = __builtin_nontemporal_load(&zbuf2[n * HW2 + q]);
        z[n][0] = v.x; z[n][1] = v.y;
    }

    bool dup0[2]; int bidx[2];
    #pragma unroll
    for (int j = 0; j < 2; ++j) {
        int count = 0; float best = __builtin_inff(); int bi = 0;
        #pragma unroll
        for (int n = 0; n < N_MESH; ++n) {
            const float zv = z[n][j];
            count += (zv > -1.0f) ? 1 : 0;
            const float t = (zv < 0.0f) ? BIG_Z_F : zv;
            if (t < best) { best = t; bi = n; }   // strict < => first-win tie
        }
        dup0[j] = (count > 1);
        bidx[j] = bi;
    }

    #pragma unroll
    for (int n = 0; n < N_MESH; ++n) {
        f2 m, zb;
        #pragma unroll
        for (int j = 0; j < 2; ++j) {
            const bool dup = dup0[j] && ((md != 0) || (n != bidx[j]));
            m[j]  = (z[n][j] >= 0.0f) ? 1.0f : 0.0f;
            zb[j] = dup ? -1.0f : z[n][j];
        }
        __builtin_nontemporal_store(m,  &maskO2[n * HW2 + q]);
        __builtin_nontemporal_store(zb, &zbO2[n * HW2 + q]);
    }
    uc2 w;
    w.x = dup0[0] ? (unsigned char)bidx[0] : (unsigned char)0xFF;
    w.y = dup0[1] ? (unsigned char)bidx[1] : (unsigned char)0xFF;
    win2[q] = w;
}

// ---------------------------------------------------------------------------
// Kernel B: per-(mesh, 4 pixels). Branchless gather/interp path; faceflag
// scatter now PREDICATED (R15: kills ~14.7M dummy-slot stores).
// ---------------------------------------------------------------------------
__global__ __launch_bounds__(256) void raster_interp(
    const i4* __restrict__ p2f4,    // (N, HW/4)
    const f4* __restrict__ bary4,   // (N, HW/4, 3)
    const f4* __restrict__ dists4,  // (N, HW/4)
    const float* __restrict__ fmem, // (F,3,C)
    const uc4* __restrict__ win4,   // (HW/4)
    const int* __restrict__ mdp,
    f4* __restrict__ out_map4,      // (N,C,HW/4)
    f4* __restrict__ pO4,           // (N, HW/4)
    f4* __restrict__ dO4,           // (N, HW/4)
    f4* __restrict__ bcO4,          // (N, HW/4, 3)
    int* __restrict__ faceflag,     // (F+1) ws, pre-zeroed
    int HW4, int C, int F)
{
    const int q = blockIdx.x * blockDim.x + threadIdx.x;
    if (q >= HW4) return;
    const int n    = blockIdx.y;
    const int idx4 = n * HW4 + q;
    const int md   = *mdp;

    const uc4 wv = win4[q];
    const unsigned char w[4] = { wv.x, wv.y, wv.z, wv.w };

    const i4 praw = __builtin_nontemporal_load(&p2f4[idx4]);
    const f4 drw  = __builtin_nontemporal_load(&dists4[idx4]);
    const f4 bv0  = __builtin_nontemporal_load(&bary4[idx4 * 3 + 0]); // p0.xyz p1.x
    const f4 bv1  = __builtin_nontemporal_load(&bary4[idx4 * 3 + 1]); // p1.yz  p2.xy
    const f4 bv2  = __builtin_nontemporal_load(&bary4[idx4 * 3 + 2]); // p2.z   p3.xyz
    const int   pr[4] = { praw.x, praw.y, praw.z, praw.w };
    const float dr[4] = { drw.x, drw.y, drw.z, drw.w };
    const float br[4][3] = {
        { bv0.x, bv0.y, bv0.z },
        { bv0.w, bv1.x, bv1.y },
        { bv1.z, bv1.w, bv2.x },
        { bv2.y, bv2.z, bv2.w },
    };

    float bst[4][3];   // values stored to bcO (dup -> -1)
    float bc[4][3];    // compute coefficients (invalid -> 0 => out = 0)
    int   safe[4];
    f4 pOv, dOv;
    #pragma unroll
    for (int j = 0; j < 4; ++j) {
        const bool dup   = (w[j] != 0xFF) && ((md != 0) || (n != (int)w[j]));
        const int  p     = dup ? -1 : pr[j];
        const bool valid = (p >= 0);
        #pragma unroll
        for (int k = 0; k < 3; ++k) {
            bst[j][k] = dup ? -1.0f : br[j][k];
            bc[j][k]  = valid ? bst[j][k] : 0.0f;
        }
        safe[j] = valid ? p : 0;
        pOv[j]  = (float)p;
        dOv[j]  = dup ? -1.0f : dr[j];
        if (valid) faceflag[p] = 1;   // R15: predicated (was dummy-slot)
    }
    __builtin_nontemporal_store(pOv, &pO4[idx4]);
    __builtin_nontemporal_store(dOv, &dO4[idx4]);
    {
        f4 c0, c1, c2;
        c0.x = bst[0][0]; c0.y = bst[0][1]; c0.z = bst[0][2]; c0.w = bst[1][0];
        c1.x = bst[1][1]; c1.y = bst[1][2]; c1.z = bst[2][0]; c1.w = bst[2][1];
        c2.x = bst[2][2]; c2.y = bst[3][0]; c2.z = bst[3][1]; c2.w = bst[3][2];
        __builtin_nontemporal_store(c0, &bcO4[idx4 * 3 + 0]);
        __builtin_nontemporal_store(c1, &bcO4[idx4 * 3 + 1]);
        __builtin_nontemporal_store(c2, &bcO4[idx4 * 3 + 2]);
    }

    const float* ab[4];
    #pragma unroll
    for (int j = 0; j < 4; ++j)
        ab[j] = fmem + (size_t)safe[j] * 3 * C;

    #pragma unroll
    for (int c4 = 0; c4 < 32; c4 += 4) {     // C == 32
        f4 r[4];   // r[j] = channels c4..c4+3 of pixel j (channel-major)
        #pragma unroll
        for (int j = 0; j < 4; ++j) {
            const float* a = ab[j];
            const f4 a0 = *(const f4*)(a + c4);
            const f4 a1 = *(const f4*)(a + C + c4);
            const f4 a2 = *(const f4*)(a + 2 * C + c4);
            r[j] = bc[j][0] * a0 + bc[j][1] * a1 + bc[j][2] * a2;
        }
        #pragma unroll
        for (int k = 0; k < 4; ++k) {        // transpose to pixel-major
            f4 o;
            o.x = r[0][k]; o.y = r[1][k]; o.z = r[2][k]; o.w = r[3][k];
            __builtin_nontemporal_store(o, &out_map4[(size_t)(n * C + c4 + k) * HW4 + q]);
        }
    }
}

// Scatter vertex visibility from face-visibility flags. (R9 exact)
__global__ __launch_bounds__(256) void vert_vis(
    const int* __restrict__ faceflag,
    const int* __restrict__ pfaces,     // (F,3)
    float* __restrict__ vv,             // (V), pre-zeroed by kernel A
    int F)
{
    const int f = blockIdx.x * blockDim.x + threadIdx.x;
    if (f >= F) return;
    if (faceflag[f]) {
        vv[pfaces[f * 3 + 0]] = 1.0f;
        vv[pfaces[f * 3 + 1]] = 1.0f;
        vv[pfaces[f * 3 + 2]] = 1.0f;
    }
}

extern "C" void kernel_launch(void* const* d_in, const int* in_sizes, int n_in,
                              void* d_out, int out_size, void* d_ws, size_t ws_size,
                              hipStream_t stream) {
    const float* zbuf   = (const float*)d_in[0];
    const int*   p2f    = (const int*)  d_in[1];
    const float* bary   = (const float*)d_in[2];
    const float* dists  = (const float*)d_in[3];
    const float* fmem   = (const float*)d_in[4];
    const int*   pfaces = (const int*)  d_in[5];
    // d_in[6] = num_verts (device scalar; V derived from out_size instead)
    const int*   mdp    = (const int*)  d_in[7];

    const long long P  = in_sizes[0];        // N*H*W*K = 2097152
    const int HW  = (int)(P / N_MESH);       // 262144 pixels
    const int HW2 = HW / 2;                  // 131072
    const int HW4 = HW / 4;                  // 65536
    const int F3  = in_sizes[5];             // F*3
    const int F   = F3 / 3;                  // 20000
    const int C   = in_sizes[4] / F3;        // 32
    const int V   = (int)((long long)out_size - P * C - 7 * P);  // 10002

    float* out     = (float*)d_out;
    float* out_map = out;                    // P*C
    float* vv      = out_map + P * C;        // V
    float* maskO   = vv + V;                 // P
    float* zbO     = maskO + P;              // P
    float* pO      = zbO + P;                // P
    float* dO      = pO + P;                 // P
    float* bcO     = dO + P;                 // 3P

    int* faceflag = (int*)d_ws;                 // F+1 ints
    uc2* win2     = (uc2*)(faceflag + F + 4);   // HW bytes
    uc4* win4     = (uc4*)win2;                 // same buffer, B's view

    raster_reduce<<<dim3(HW2 / 256), dim3(256), 0, stream>>>(
        (const f2*)zbuf, (f2*)maskO, (f2*)zbO, win2, faceflag, vv, mdp,
        HW2, F, V);

    raster_interp<<<dim3(HW4 / 256, N_MESH), dim3(256), 0, stream>>>(
        (const i4*)p2f, (const f4*)bary, (const f4*)dists, fmem,
        (const uc4*)win4, mdp,
        (f4*)out_map, (f4*)pO, (f4*)dO, (f4*)bcO,
        faceflag, HW4, C, F);

    vert_vis<<<dim3((F + 255) / 256), dim3(256), 0, stream>>>(
        faceflag, pfaces, vv, F);
}